// Round 18
// baseline (312.690 us; speedup 1.0000x reference)
//
#include <hip/hip_runtime.h>
#include <stdint.h>

// Problem constants (fixed by setup_inputs)
#define B_ 4
#define L_ 4096
#define DM 1024
#define H_ 16
#define D_ 64
#define BH (B_*H_)      // 64
#define N_ (B_*L_)      // 16384
#define CS 128          // chunk size for causal attention
#define NC (L_/CS)      // 32
#define SC 64           // chunk size for normalizer scans
#define NSC (L_/SC)     // 64
#define EPSF 1e-6f

typedef unsigned short u16;
typedef unsigned int   u32;
typedef __attribute__((ext_vector_type(8))) short s16x8;
typedef __attribute__((ext_vector_type(4))) float f32x4;

__device__ __forceinline__ float bf2f(u16 u){
  union { u32 i; float f; } v; v.i = ((u32)u) << 16; return v.f;
}
__device__ __forceinline__ u16 f2bf(float f){
  union { float f; u32 i; } v; v.f = f;
  u32 i = v.i;
  return (u16)((i + 0x7fffu + ((i >> 16) & 1u)) >> 16);  // RNE
}
__device__ __forceinline__ void gload16(const void* g, void* l){
  __builtin_amdgcn_global_load_lds(
      (const __attribute__((address_space(1))) u32*)g,
      (__attribute__((address_space(3))) u32*)l, 16, 0, 0);
}
__device__ __forceinline__ f32x4 mfma16(s16x8 a, s16x8 b, f32x4 c){
  return __builtin_amdgcn_mfma_f32_16x16x32_bf16(a, b, c, 0, 0, 0);
}
__device__ __forceinline__ float sigmoidf_(float x){ return 1.0f/(1.0f+__expf(-x)); }

// Masked ordered prefix-reduction over chunk sums (R16, measured good).
__device__ __forceinline__ float prefix_sum64(const float* __restrict__ sums,
                                              int bh, int sc, int lane){
  float run = 0.f;
  for (int g = 0; g < NSC; g += 16){
    float tv[16];
    #pragma unroll
    for (int j = 0; j < 16; j++)
      tv[j] = sums[((size_t)bh*NSC + g + j)*64 + lane];
    #pragma unroll
    for (int j = 0; j < 16; j++)
      if (g + j < sc) run += tv[j];
  }
  return run;
}

// ---------------- prep: fp32->bf16 cvt + 4x W transpose (one launch) ----------------
__global__ __launch_bounds__(256) void prep_kernel(
    const float* __restrict__ x,
    const float* __restrict__ Wq, const float* __restrict__ Wk,
    const float* __restrict__ Wv, const float* __restrict__ Wo,
    u16* __restrict__ xb, u16* __restrict__ wqkvT, u16* __restrict__ woT){
  __shared__ float t[64][65];
  int bid = blockIdx.x;
  if (bid < 16384){
    int i = bid * 256 + threadIdx.x;          // over N_*DM/4 = 4194304
    float4 v = ((const float4*)x)[i];
    union { u16 s[4]; uint2 u; } o;
    o.s[0]=f2bf(v.x); o.s[1]=f2bf(v.y); o.s[2]=f2bf(v.z); o.s[3]=f2bf(v.w);
    ((uint2*)xb)[i] = o.u;
    return;
  }
  int w = bid - 16384;
  int z = w >> 8, w2 = w & 255;
  const float* W = (z==0) ? Wq : (z==1) ? Wk : (z==2) ? Wv : Wo;
  u16* WT = (z<3) ? (wqkvT + (size_t)z*DM*DM) : woT;
  int n0 = (w2 & 15) * 64, k0 = (w2 >> 4) * 64;
  int tx = threadIdx.x & 63, ty = threadIdx.x >> 6;
  #pragma unroll
  for (int s = 0; s < 64; s += 4)
    t[ty + s][tx] = W[(size_t)(k0 + ty + s) * DM + n0 + tx];
  __syncthreads();
  #pragma unroll
  for (int s = 0; s < 64; s += 4)
    WT[(size_t)(n0 + ty + s) * DM + k0 + tx] = f2bf(t[tx][ty + s]);
}

// ---------------- 256x256 MFMA GEMM, BK=32, 64KB LDS -> 2 blocks/CU ----------------
// New-evidence revision (R18): at BK=64/128KB the kernel is 1 block/CU (2 waves/SIMD);
// LDS-read (~2260cy) and MFMA (~2060cy) per tile run near-serial (measured 6700cy/tile,
// MfmaUtil 32%). BK=32 halves LDS -> 2 blocks/CU: cross-block TLP overlaps one block's
// stage/barrier/ds_read with the other's MFMA. Per-wave tile stays 128x64 (same
// bytes/FLOP). Read swizzle phys = q ^ ((fr+(fr>>2))&3): 2-way residual = free.
// Ledger: 4 gloads/STAGE, distance 2, vmcnt(4) per consume, vmcnt(0) only at t=31.
template<int QKV>
__global__ __launch_bounds__(512, 2) void gemm256_kernel(
    const u16* __restrict__ A, const u16* __restrict__ BT,
    const float* __restrict__ biasq, const float* __restrict__ biask, const float* __restrict__ biasv,
    u16* __restrict__ oq, u16* __restrict__ ok, u16* __restrict__ ov,
    float* __restrict__ outf,
    float* __restrict__ sumQ, float* __restrict__ sumK, int NBY)
{
  // LDS bytes: A slot0 [0,16K), A slot1 [16K,32K), B slot0 [32K,48K), B slot1 [48K,64K)
  __shared__ __align__(16) u16 smem[32768];
  char* smb = (char*)smem;
  int tid = threadIdx.x;
  int wave = tid >> 6, lane = tid & 63;
  int wm = wave >> 2, wn = wave & 3;          // 2 x 4 wave grid
  int nwg = gridDim.x;
  int q8 = nwg >> 3;
  int id = blockIdx.x;
  int id2 = (id & 7) * q8 + (id >> 3);
  int bx = id2 / NBY, by = id2 % NBY;
  int m0 = bx * 256, n0 = by * 256;
  // staging: pass i covers rows i*128 + (tid>>2); phys chunk tid&3; source chunk
  // pre-swizzled with sw(row) = (row + (row>>2)) & 3 = ((tid>>2)+(tid>>4)) & 3 (pass-invariant)
  int srcq = (tid & 3) ^ (((tid >> 2) + (tid >> 4)) & 3);
  const u16* aRow = A  + (size_t)(m0 + (tid >> 2)) * 1024 + srcq * 8;
  const u16* bRow = BT + (size_t)(n0 + (tid >> 2)) * 1024 + srcq * 8;

  f32x4 acc[8][4];
  #pragma unroll
  for (int i=0;i<8;i++)
    #pragma unroll
    for (int j=0;j<4;j++) acc[i][j] = (f32x4){0.f,0.f,0.f,0.f};

  int fr = lane & 15, q = lane >> 4;
  // read offset within a [rows][32] tile: row fr (+16*mi handled by +1024B), chunk
  // phys = q ^ ((fr + (fr>>2)) & 3); 16-multiples of row are ≡0 mod 4 so fr alone decides
  int aoff = fr*64 + ((q ^ ((fr + (fr >> 2)) & 3)) << 4);

  #define STAGE(s, t) { \
    gload16(aRow + (size_t)(t)*32,          smb + (s)*16384 + tid*16); \
    gload16(aRow + (size_t)(t)*32 + 131072, smb + (s)*16384 + 8192 + tid*16); \
    gload16(bRow + (size_t)(t)*32,          smb + 32768 + (s)*16384 + tid*16); \
    gload16(bRow + (size_t)(t)*32 + 131072, smb + 32768 + (s)*16384 + 8192 + tid*16); \
  }

  #define COMPUTE(s) { \
    const char* Ab_ = smb + (s)*16384 + wm*8192; \
    const char* Bb_ = smb + 32768 + (s)*16384 + wn*4096; \
    s16x8 af_[8], bf_[4]; \
    _Pragma("unroll") \
    for (int mi_ = 0; mi_ < 8; mi_++) af_[mi_] = *(const s16x8*)(Ab_ + mi_*1024 + aoff); \
    _Pragma("unroll") \
    for (int ni_ = 0; ni_ < 4; ni_++) bf_[ni_] = *(const s16x8*)(Bb_ + ni_*1024 + aoff); \
    _Pragma("unroll") \
    for (int mi_ = 0; mi_ < 8; mi_++) \
      _Pragma("unroll") \
      for (int ni_ = 0; ni_ < 4; ni_++) \
        acc[mi_][ni_] = mfma16(af_[mi_], bf_[ni_], acc[mi_][ni_]); \
  }

  STAGE(0, 0)
  STAGE(1, 1)
  for (int t = 0; t < 30; t++){
    asm volatile("s_waitcnt vmcnt(4)" ::: "memory");
    __builtin_amdgcn_s_barrier();
    asm volatile("" ::: "memory");
    COMPUTE(t & 1)
    asm volatile("s_waitcnt lgkmcnt(0)" ::: "memory");
    __builtin_amdgcn_s_barrier();
    asm volatile("" ::: "memory");
    STAGE(t & 1, t + 2)
  }
  asm volatile("s_waitcnt vmcnt(4)" ::: "memory");
  __builtin_amdgcn_s_barrier();
  asm volatile("" ::: "memory");
  COMPUTE(0)
  asm volatile("s_waitcnt vmcnt(0)" ::: "memory");
  __builtin_amdgcn_s_barrier();
  asm volatile("" ::: "memory");
  COMPUTE(1)

  // epilogue
  int colblk = n0 + wn*64;
  int which  = QKV ? (colblk >> 10) : 0;          // 0=q 1=k 2=v
  int cl0    = QKV ? (colblk & 1023) : colblk;
  const float* bias = QKV ? (which==0 ? biasq : (which==1 ? biask : biasv)) : biasq;
  u16* outp = QKV ? (which==0 ? oq : (which==1 ? ok : ov)) : (u16*)0;
  float cs0[4] = {0.f,0.f,0.f,0.f}, cs1[4] = {0.f,0.f,0.f,0.f};
  #pragma unroll
  for (int mi = 0; mi < 8; mi++){
    int row = m0 + wm*128 + mi*16 + (lane>>4)*4;
    #pragma unroll
    for (int ni = 0; ni < 4; ni++){
      int cl = cl0 + ni*16 + fr;
      float bv = bias[cl];
      #pragma unroll
      for (int r = 0; r < 4; r++){
        float val = acc[mi][ni][r] + bv;
        if (QKV){
          if (which < 2) val = sigmoidf_(val);
          outp[(size_t)(row + r) * 1024 + cl] = f2bf(val);
          if (which < 2){ if (mi < 4) cs0[ni] += val; else cs1[ni] += val; }
        } else {
          outf[(size_t)(row + r) * 1024 + cl] = val;
        }
      }
    }
  }
  if (QKV && which < 2){
    float* sums = (which==0) ? sumQ : sumK;
    int bh = (m0 >> 12) * H_ + ((colblk & 1023) >> 6);
    int sc0 = ((m0 & 4095) >> 6) + wm*2;
    #pragma unroll
    for (int h2 = 0; h2 < 2; h2++){
      #pragma unroll
      for (int ni = 0; ni < 4; ni++){
        float s = h2 ? cs1[ni] : cs0[ni];
        s += __shfl_xor(s, 16);
        s += __shfl_xor(s, 32);
        if (lane < 16) sums[((size_t)bh*NSC + sc0 + h2)*64 + ni*16 + fr] = s;
      }
    }
  }
  #undef STAGE
  #undef COMPUTE
}

// ---------------- fused sink_incoming/source_outgoing + mod chunk sums (R16) ----------------
__global__ __launch_bounds__(128) void siso_fused_kernel(
    const u16* __restrict__ q, const u16* __restrict__ k,
    const float* __restrict__ sumQ, const float* __restrict__ sumK,
    float* __restrict__ si, float* __restrict__ so,
    float* __restrict__ sumQsi, float* __restrict__ sumKso)
{
  __shared__ u16 cq[64*64];
  __shared__ u16 ck[64*64];
  __shared__ float siv[64], sov[64];
  int bhc = blockIdx.x; int bh = bhc >> 6, sc = bhc & 63;
  int b = bh >> 4, h = bh & 15;
  int tid = threadIdx.x, w = tid >> 6, lane = tid & 63;
  size_t gbase = ((size_t)(b*L_ + sc*SC))*DM + h*D_;
  size_t lb = (size_t)bh*L_ + sc*SC;
  const u16* src = w ? k : q;
  u16* ldsT = w ? ck : cq;
  float run = prefix_sum64(w ? sumK : sumQ, bh, sc, lane);
  // P0: stage raw tile, swizzled
  {
    int r8 = lane >> 3, c8 = (lane & 7) * 8;
    #pragma unroll
    for (int j = 0; j < 8; j++){
      int l = j*8 + r8;
      uint4 u = *(const uint4*)(src + gbase + (size_t)l*DM + c8);
      const u16* up = (const u16*)&u;
      #pragma unroll
      for (int e = 0; e < 8; e++)
        ldsT[l*64 + ((c8 + e) ^ (l & 31))] = up[e];
    }
  }
  __syncthreads();
  // P1: column cumsum in place (lane = d)
  {
    for (int l = 0; l < SC; l++){
      int sw = lane ^ (l & 31);
      run += bf2f(ldsT[l*64 + sw]);
      ldsT[l*64 + sw] = f2bf(run);
    }
  }
  __syncthreads();
  // P2: row dots
  uint4 rowreg[8];
  {
    int l = lane;
    const u16* row = src + gbase + (size_t)l*DM;
    #pragma unroll
    for (int j=0;j<8;j++) rowreg[j] = ((const uint4*)row)[j];
    const u16* rp = (const u16*)rowreg;
    const u16* other = w ? cq : ck;
    float acc = 0.f;
    #pragma unroll
    for (int d = 0; d < 64; d++){
      int sw = d ^ (l & 31);
      acc += (bf2f(rp[d])+EPSF) * (bf2f(other[l*64+sw])+EPSF);
    }
    float n = (float)(sc*SC + l + 1);
    float vv = n / acc;
    if (w == 0){ si[lb+l] = vv; siv[l] = vv; }
    else       { so[lb+l] = vv; sov[l] = vv; }
  }
  __syncthreads();
  // P2b: raw rows back over dead cumsums
  {
    int l = lane;
    const u16* rp = (const u16*)rowreg;
    #pragma unroll
    for (int d = 0; d < 64; d++)
      ldsT[l*64 + (d ^ (l & 31))] = rp[d];
  }
  __syncthreads();
  // P3: column mod-sums (lane = d)
  {
    const float* sv = w ? sov : siv;
    float s = 0.f;
    for (int l = 0; l < SC; l++){
      int sw = lane ^ (l & 31);
      s += bf2f(ldsT[l*64 + sw]) * sv[l];
    }
    if (w == 0) sumQsi[bhc*64 + lane] = s;
    else        sumKso[bhc*64 + lane] = s;
  }
}

// ---------------- fused conserved_sink/source -> sall, csrc + exp chunk sums (R16) ----------------
__global__ __launch_bounds__(128) void cons_fused_kernel(
    const u16* __restrict__ q, const u16* __restrict__ k,
    const float* __restrict__ si, const float* __restrict__ so,
    const float* __restrict__ sumQsi, const float* __restrict__ sumKso,
    float* __restrict__ csrc, float* __restrict__ sall, float* __restrict__ csSum)
{
  __shared__ u16 cq[64*64];
  __shared__ u16 ck[64*64];
  __shared__ float siv[64], sov[64];
  int bhc = blockIdx.x; int bh = bhc >> 6, sc = bhc & 63;
  int b = bh >> 4, h = bh & 15;
  int tid = threadIdx.x, w = tid >> 6, lane = tid & 63;
  size_t gbase = ((size_t)(b*L_ + sc*SC))*DM + h*D_;
  size_t lb = (size_t)bh*L_ + sc*SC;
  const u16* src = w ? k : q;
  u16* ldsT = w ? ck : cq;
  if (w == 0) siv[lane] = si[lb + lane];
  else        sov[lane] = so[lb + lane];
  float run = prefix_sum64(w ? sumKso : sumQsi, bh, sc, lane);
  // P0: stage raw tile, swizzled
  {
    int r8 = lane >> 3, c8 = (lane & 7) * 8;
    #pragma unroll
    for (int j = 0; j < 8; j++){
      int l = j*8 + r8;
      uint4 u = *(const uint4*)(src + gbase + (size_t)l*DM + c8);
      const u16* up = (const u16*)&u;
      #pragma unroll
      for (int e = 0; e < 8; e++)
        ldsT[l*64 + ((c8 + e) ^ (l & 31))] = up[e];
    }
  }
  __syncthreads();
  // P1: weighted column cumsum in place
  {
    const float* sv = w ? sov : siv;
    for (int l = 0; l < SC; l++){
      int sw = lane ^ (l & 31);
      run += bf2f(ldsT[l*64 + sw]) * sv[l];
      ldsT[l*64 + sw] = f2bf(run);
    }
  }
  __syncthreads();
  // P2: row dots
  {
    int l = lane;
    const u16* row = src + gbase + (size_t)l*DM;
    uint4 rr[8];
    #pragma unroll
    for (int j=0;j<8;j++) rr[j] = ((const uint4*)row)[j];
    const u16* rp = (const u16*)rr;
    const u16* other = w ? cq : ck;
    float acc = 0.f;
    #pragma unroll
    for (int d = 0; d < 64; d++){
      int sw = d ^ (l & 31);
      acc += (bf2f(rp[d])+EPSF) * (bf2f(other[l*64+sw])+EPSF);
    }
    float inv = 1.0f / (float)(sc*SC + l + 1);
    if (w == 0){
      sall[lb+l] = sigmoidf_(acc * inv);
    } else {
      float cs = acc * inv;
      csrc[lb+l] = cs;
      float e = __expf(cs);
      #pragma unroll
      for (int off = 32; off > 0; off >>= 1) e += __shfl_xor(e, off);
      if (lane == 0) csSum[bhc] = e;
    }
  }
}

// ---------------- per-chunk VK sums via MFMA + scomp fused; bf16 chunk output ----------------
__global__ __launch_bounds__(256) void vk_chunk_kernel(
    const u16* __restrict__ k, const u16* __restrict__ v,
    const float* __restrict__ csrc, const float* __restrict__ csSum,
    float* __restrict__ scomp, u16* __restrict__ vkc16){
  __shared__ __align__(16) u16 vt[64*128];   // (v*scomp)^T [m][l] swz
  __shared__ __align__(16) u16 kt[64*128];   // k^T [d][l] swz
  __shared__ float scmpv[128];
  int bhc = blockIdx.x; int bh = bhc >> 5, c = bhc & 31;
  int b = bh >> 4, h = bh & 15;
  int tid = threadIdx.x, wave = tid >> 6, lane = tid & 63;
  size_t gbase = ((size_t)(b * L_ + c * CS)) * DM + h * D_;
  // Phase A: scmp for scan-chunks sc = 2c + {0,1}
  if (wave < 2){
    int sc = c*2 + wave;
    float v2 = (lane < sc) ? csSum[bh*NSC + lane] : 0.f;
    #pragma unroll
    for (int o = 32; o > 0; o >>= 1) v2 += __shfl_xor(v2, o);
    float off = v2;
    size_t idx = (size_t)bh * L_ + sc * SC + lane;
    float cs = __expf(csrc[idx]);
    float run = cs;
    #pragma unroll
    for (int o = 1; o < 64; o <<= 1){
      float t = __shfl_up(run, o);
      if (lane >= o) run += t;
    }
    float sm = cs / (off + run) * (float)(sc*SC + lane + 1);
    scomp[idx] = sm;
    scmpv[wave*64 + lane] = sm;
  }
  __syncthreads();
  // Phase B: stage transposed tiles (v scaled by scmp from LDS)
  {
    int r = tid >> 1;            // source row l = 0..127
    int cc = (tid & 1) * 32;     // d-half
    float vscale = scmpv[r];
    #pragma unroll
    for (int j = 0; j < 4; j++){
      uint4 ku = *(const uint4*)(k + gbase + (size_t)r * DM + cc + j*8);
      uint4 vu = *(const uint4*)(v + gbase + (size_t)r * DM + cc + j*8);
      const u16* kp = (const u16*)&ku; const u16* vp = (const u16*)&vu;
      #pragma unroll
      for (int e = 0; e < 8; e++){
        int m = cc + j*8 + e;
        int idx = m*128 + ((((r >> 3) ^ (m & 7)) << 3) | (r & 7));
        vt[idx] = f2bf(bf2f(vp[e]) * vscale);
        kt[idx] = kp[e];
      }
    }
  }
  __syncthreads();
  int fr = lane & 15, q = lane >> 4;
  int mt = wave;                 // m-tile (16 rows) per wave
  f32x4 acc[4];
  #pragma unroll
  for (int i = 0; i < 4; i++) acc[i] = (f32x4){0.f,0.f,0.f,0.f};
  #pragma unroll
  for (int ks = 0; ks < 4; ks++){
    int lc = ks*4 + q;           // logical 16B l-chunk
    int off = ((lc ^ (fr & 7)) << 3);
    s16x8 av = *(const s16x8*)&vt[(mt*16 + fr)*128 + off];
    #pragma unroll
    for (int nt = 0; nt < 4; nt++){
      s16x8 bk = *(const s16x8*)&kt[(nt*16 + fr)*128 + off];
      acc[nt] = mfma16(av, bk, acc[nt]);
    }
  }
  u16* outp = vkc16 + (size_t)bhc * (D_*D_);
  #pragma unroll
  for (int nt = 0; nt < 4; nt++)
    #pragma unroll
    for (int r = 0; r < 4; r++)
      outp[(mt*16 + q*4 + r)*64 + nt*16 + fr] = f2bf(acc[nt][r]);
}

// ---------------- exclusive scan of VK over chunks: bf16 in -> bf16 prefix out ----------------
__global__ __launch_bounds__(256) void vk_scan_kernel(const u16* __restrict__ vkc16, u16* __restrict__ vkb){
  int idx = blockIdx.x * 256 + threadIdx.x;   // over BH*4096
  int bh = idx >> 12;
  int e  = idx & 4095;
  size_t base = ((size_t)bh * NC) * 4096 + e;
  float run = 0.f;
  for (int g = 0; g < NC; g += 16){
    u16 tv[16];
    #pragma unroll
    for (int j = 0; j < 16; j++) tv[j] = vkc16[base + (size_t)(g + j) * 4096];
    #pragma unroll
    for (int j = 0; j < 16; j++){
      vkb[base + (size_t)(g + j) * 4096] = f2bf(run);
      run += bf2f(tv[j]);
    }
  }
}

// ---------------- causal attention per (bh, chunk) — R17 (overlapped, measured good) ----------------
__global__ __launch_bounds__(256) void attn_kernel(
    const u16* __restrict__ q, const u16* __restrict__ k, const u16* __restrict__ v,
    const float* __restrict__ si, const float* __restrict__ scomp, const float* __restrict__ salloc,
    const u16* __restrict__ vkb, u16* __restrict__ attnout)
{
  __shared__ __align__(16) u16 qs[128*64];    // qmod rows [l][d] swz; reused as ss0
  __shared__ __align__(16) u16 ks2[128*64];   // k rows    [j][d] swz
  __shared__ __align__(16) u16 vts[64*128];   // (v*scomp)^T [m][j] swz
  __shared__ __align__(16) u16 vks[64*64];    // VKprev [m][d] swz
  __shared__ __align__(16) u16 ss[128*64];    // S strip for jt2=1 (ss1)
  int bhc = blockIdx.x; int bh = bhc >> 5, c = bhc & 31;
  int b = bh >> 4, h = bh & 15;
  int tid = threadIdx.x, wave = tid >> 6, lane = tid & 63;
  size_t gbase = ((size_t)(b * L_ + c * CS)) * DM + h * D_;
  size_t sbase = (size_t)bh * L_ + c * CS;
  {
    int r = tid >> 1;
    int cc = (tid & 1) * 32;
    int l = c * CS + r;
    float qscale = si[sbase + r] / (float)(l + 1);
    float vscale = scomp[sbase + r];
    #pragma unroll
    for (int j = 0; j < 4; j++){
      int d0 = cc + j*8;
      uint4 qu = *(const uint4*)(q + gbase + (size_t)r * DM + d0);
      uint4 kuv = *(const uint4*)(k + gbase + (size_t)r * DM + d0);
      uint4 vu = *(const uint4*)(v + gbase + (size_t)r * DM + d0);
      const u16* qp = (const u16*)&qu; const u16* vp = (const u16*)&vu;
      u16 tmp[8];
      #pragma unroll
      for (int e = 0; e < 8; e++) tmp[e] = f2bf(bf2f(qp[e]) * qscale);
      int csw = ((d0 >> 3) ^ (r & 7)) << 3;           // swizzled d-chunk
      *(uint4*)&qs[r*64 + csw]  = *(uint4*)tmp;
      *(uint4*)&ks2[r*64 + csw] = kuv;
      #pragma unroll
      for (int e = 0; e < 8; e++){
        int m = d0 + e;
        int jsw = (((r >> 3) ^ (m & 7)) << 3) | (r & 7);  // swizzled j position
        vts[m*128 + jsw] = f2bf(bf2f(vp[e]) * vscale);
      }
    }
    const u16* vkp = vkb + (size_t)bhc * (D_*D_) + tid * 16;
    int m = tid >> 2, dq = (tid & 3) * 2;               // two d-chunks per thread
    int o0 = ((dq     ^ (m & 7)) << 3);
    int o1 = (((dq+1) ^ (m & 7)) << 3);
    *(uint4*)&vks[m*64 + o0] = *(const uint4*)(vkp);
    *(uint4*)&vks[m*64 + o1] = *(const uint4*)(vkp + 8);
  }
  __syncthreads();                 // B0: staging visible
  int t0 = wave, t1 = 7 - wave;    // balanced l-tile pair per wave
  int fr = lane & 15, qh = lane >> 4;
  int f7 = fr & 7;
  f32x4 acc[2][4];
  #pragma unroll
  for (int i=0;i<2;i++)
    #pragma unroll
    for (int j=0;j<4;j++) acc[i][j] = (f32x4){0.f,0.f,0.f,0.f};
  s16x8 aq[2][2];
  #pragma unroll
  for (int ti = 0; ti < 2; ti++){
    int t = ti ? t1 : t0;
    #pragma unroll
    for (int kk = 0; kk < 2; kk++){
      int oc = (((kk*4 + qh) ^ f7) << 3);
      aq[ti][kk] = *(const s16x8*)&qs[(t*16 + fr)*64 + oc];
    }
  }
  __syncthreads();                 // B-A: all aq loads done; qs region now dead
  // inter-chunk MFMA + QK half0 (S -> qs region)
  #pragma unroll
  for (int mt = 0; mt < 4; mt++){
    #pragma unroll
    for (int kk = 0; kk < 2; kk++){
      int oc = (((kk*4 + qh) ^ f7) << 3);
      s16x8 bv = *(const s16x8*)&vks[(mt*16 + fr)*64 + oc];
      acc[0][mt] = mfma16(aq[0][kk], bv, acc[0][mt]);
      acc[1][mt] = mfma16(aq[1][kk], bv, acc[1][mt]);
    }
  }
  #define QK_HALF(jt2, dst) \
    _Pragma("unroll") \
    for (int ti = 0; ti < 2; ti++){ \
      int t = ti ? t1 : t0; \
      _Pragma("unroll") \
      for (int u = 0; u < 4; u++){ \
        int jj = (jt2)*4 + u; \
        f32x4 sacc = (f32x4){0.f,0.f,0.f,0.f}; \
        if (jj <= t){ \
          _Pragma("unroll") \
          for (int kk = 0; kk < 2; kk++){ \
            int oc = (((kk*4 + qh) ^ f7) << 3); \
            s16x8 bkf = *(const s16x8*)&ks2[(jj*16 + fr)*64 + oc]; \
            sacc = mfma16(aq[ti][kk], bkf, sacc); \
          } \
        } \
        int lrow = t*16 + qh*4; \
        int jcol = jj*16 + fr; \
        int cst = u*2 + (fr >> 3); \
        _Pragma("unroll") \
        for (int r = 0; r < 4; r++){ \
          float sv = (jcol <= lrow + r) ? sacc[r] : 0.f; \
          int row = lrow + r; \
          dst[row*64 + (((cst ^ (row & 7)) << 3) | f7)] = f2bf(sv); \
        } \
      } \
    }
  #define PV_HALF(jt2, srcb) \
    _Pragma("unroll") \
    for (int ti = 0; ti < 2; ti++){ \
      int t = ti ? t1 : t0; \
      _Pragma("unroll") \
      for (int ks = 0; ks < 2; ks++){ \
        if ((jt2)*64 + ks*32 <= t*16 + 15){ \
          int ocs = (((ks*4 + qh) ^ f7) << 3); \
          s16x8 as = *(const s16x8*)&srcb[(t*16 + fr)*64 + ocs]; \
          _Pragma("unroll") \
          for (int mt = 0; mt < 4; mt++){ \
            int lc = (jt2)*8 + ks*4 + qh; \
            int ocv = ((lc ^ f7) << 3); \
            s16x8 bvv = *(const s16x8*)&vts[(mt*16 + fr)*128 + ocv]; \
            acc[ti][mt] = mfma16(as, bvv, acc[ti][mt]); \
          } \
        } \
      } \
    }
  QK_HALF(0, qs)
  __syncthreads();                 // B-B: ss0 (qs region) complete
  QK_HALF(1, ss)                   // overlaps PV0 below (disjoint buffers)
  PV_HALF(0, qs)
  __syncthreads();                 // B-C: ss1 complete, PV0 done
  PV_HALF(1, ss)
  #undef QK_HALF
  #undef PV_HALF
  // epilogue: * sink_allocation, write bf16 [B,L,DM]
  #pragma unroll
  for (int ti = 0; ti < 2; ti++){
    int t = ti ? t1 : t0;
    int lrow = t*16 + qh*4;
    #pragma unroll
    for (int r = 0; r < 4; r++){
      float sa = salloc[sbase + lrow + r];
      size_t orow = ((size_t)(b * L_ + c * CS + lrow + r)) * DM + h * D_;
      #pragma unroll
      for (int mt = 0; mt < 4; mt++){
        attnout[orow + mt*16 + fr] = f2bf(acc[ti][mt][r] * sa);
      }
    }
  }
}

extern "C" void kernel_launch(void* const* d_in, const int* in_sizes, int n_in,
                              void* d_out, int out_size, void* d_ws, size_t ws_size,
                              hipStream_t stream){
  (void)in_sizes; (void)n_in; (void)out_size; (void)ws_size;
  const float* x  = (const float*)d_in[0];
  const float* Wq = (const float*)d_in[1];
  const float* bq = (const float*)d_in[2];
  const float* Wk = (const float*)d_in[3];
  const float* bk = (const float*)d_in[4];
  const float* Wv = (const float*)d_in[5];
  const float* bv = (const float*)d_in[6];
  const float* Wo = (const float*)d_in[7];
  const float* bo = (const float*)d_in[8];

  char* p = (char*)d_ws;
  auto carve = [&](size_t bytes) -> void* {
    void* r = (void*)p; p += (bytes + 255) & ~(size_t)255; return r;
  };
  u16* xb    = (u16*)carve((size_t)N_*DM*2);
  u16* wqkvT = (u16*)carve((size_t)3*DM*DM*2);
  u16* woT   = (u16*)carve((size_t)DM*DM*2);
  u16* qb  = (u16*)carve((size_t)N_*DM*2);
  u16* kb  = (u16*)carve((size_t)N_*DM*2);
  u16* vb  = (u16*)carve((size_t)N_*DM*2);
  u16* ao  = (u16*)carve((size_t)N_*DM*2);
  float* si   = (float*)carve((size_t)BH*L_*4);
  float* so   = (float*)carve((size_t)BH*L_*4);
  float* csrc = (float*)carve((size_t)BH*L_*4);
  float* sall = (float*)carve((size_t)BH*L_*4);
  float* scmp = (float*)carve((size_t)BH*L_*4);
  float* sumQ   = (float*)carve((size_t)BH*NSC*D_*4);
  float* sumK   = (float*)carve((size_t)BH*NSC*D_*4);
  float* sumQsi = (float*)carve((size_t)BH*NSC*D_*4);
  float* sumKso = (float*)carve((size_t)BH*NSC*D_*4);
  float* csSum  = (float*)carve((size_t)BH*NSC*4);
  u16*   vkc16  = (u16*)carve((size_t)BH*NC*(size_t)(D_*D_)*2);
  u16*   vkb    = (u16*)carve((size_t)BH*NC*(size_t)(D_*D_)*2);

  // 1. prep: cvt + 4 weight transposes (one launch)
  prep_kernel<<<16384 + 4*256, 256, 0, stream>>>(x, Wq, Wk, Wv, Wo, xb, wqkvT, woT);
  // 2. fused q,k,v projection (one 16384x3072x1024 GEMM) + per-scan-chunk sums
  gemm256_kernel<1><<<dim3((N_/256)*(3*DM/256)), 512, 0, stream>>>(
      xb, wqkvT, bq, bk, bv, qb, kb, vb, nullptr, sumQ, sumK, 3*DM/256);
  // 3. normalizer pipeline (chunk prefixes inlined)
  siso_fused_kernel<<<BH*NSC, 128, 0, stream>>>(qb, kb, sumQ, sumK, si, so, sumQsi, sumKso);
  cons_fused_kernel<<<BH*NSC, 128, 0, stream>>>(qb, kb, si, so, sumQsi, sumKso, csrc, sall, csSum);
  // 4. causal linear attention (scomp fused into vk_chunk; bf16 VK chain)
  vk_chunk_kernel<<<BH*NC, 256, 0, stream>>>(kb, vb, csrc, csSum, scmp, vkc16);
  vk_scan_kernel<<<(BH*D_*D_)/256, 256, 0, stream>>>(vkc16, vkb);
  attn_kernel<<<BH*NC, 256, 0, stream>>>(qb, kb, vb, si, scmp, sall, vkb, ao);
  // 5. output projection
  gemm256_kernel<0><<<dim3((N_/256)*(DM/256)), 512, 0, stream>>>(
      ao, woT, bo, bo, bo, nullptr, nullptr, nullptr, (float*)d_out, nullptr, nullptr, DM/256);
}

// Round 19
// 308.589 us; speedup vs baseline: 1.0133x; 1.0133x over previous
//
#include <hip/hip_runtime.h>
#include <stdint.h>

// Problem constants (fixed by setup_inputs)
#define B_ 4
#define L_ 4096
#define DM 1024
#define H_ 16
#define D_ 64
#define BH (B_*H_)      // 64
#define N_ (B_*L_)      // 16384
#define CS 128          // chunk size for causal attention
#define NC (L_/CS)      // 32
#define SC 64           // chunk size for normalizer scans
#define NSC (L_/SC)     // 64
#define EPSF 1e-6f

typedef unsigned short u16;
typedef unsigned int   u32;
typedef __attribute__((ext_vector_type(8))) short s16x8;
typedef __attribute__((ext_vector_type(4))) float f32x4;

__device__ __forceinline__ float bf2f(u16 u){
  union { u32 i; float f; } v; v.i = ((u32)u) << 16; return v.f;
}
__device__ __forceinline__ u16 f2bf(float f){
  union { float f; u32 i; } v; v.f = f;
  u32 i = v.i;
  return (u16)((i + 0x7fffu + ((i >> 16) & 1u)) >> 16);  // RNE
}
__device__ __forceinline__ void gload16(const void* g, void* l){
  __builtin_amdgcn_global_load_lds(
      (const __attribute__((address_space(1))) u32*)g,
      (__attribute__((address_space(3))) u32*)l, 16, 0, 0);
}
__device__ __forceinline__ f32x4 mfma16(s16x8 a, s16x8 b, f32x4 c){
  return __builtin_amdgcn_mfma_f32_16x16x32_bf16(a, b, c, 0, 0, 0);
}
__device__ __forceinline__ float sigmoidf_(float x){ return 1.0f/(1.0f+__expf(-x)); }

// Masked ordered prefix-reduction over chunk sums (R16, measured good).
__device__ __forceinline__ float prefix_sum64(const float* __restrict__ sums,
                                              int bh, int sc, int lane){
  float run = 0.f;
  for (int g = 0; g < NSC; g += 16){
    float tv[16];
    #pragma unroll
    for (int j = 0; j < 16; j++)
      tv[j] = sums[((size_t)bh*NSC + g + j)*64 + lane];
    #pragma unroll
    for (int j = 0; j < 16; j++)
      if (g + j < sc) run += tv[j];
  }
  return run;
}

// ---------------- prep: fp32->bf16 cvt + 4x W transpose (one launch) ----------------
__global__ __launch_bounds__(256) void prep_kernel(
    const float* __restrict__ x,
    const float* __restrict__ Wq, const float* __restrict__ Wk,
    const float* __restrict__ Wv, const float* __restrict__ Wo,
    u16* __restrict__ xb, u16* __restrict__ wqkvT, u16* __restrict__ woT){
  __shared__ float t[64][65];
  int bid = blockIdx.x;
  if (bid < 16384){
    int i = bid * 256 + threadIdx.x;          // over N_*DM/4 = 4194304
    float4 v = ((const float4*)x)[i];
    union { u16 s[4]; uint2 u; } o;
    o.s[0]=f2bf(v.x); o.s[1]=f2bf(v.y); o.s[2]=f2bf(v.z); o.s[3]=f2bf(v.w);
    ((uint2*)xb)[i] = o.u;
    return;
  }
  int w = bid - 16384;
  int z = w >> 8, w2 = w & 255;
  const float* W = (z==0) ? Wq : (z==1) ? Wk : (z==2) ? Wv : Wo;
  u16* WT = (z<3) ? (wqkvT + (size_t)z*DM*DM) : woT;
  int n0 = (w2 & 15) * 64, k0 = (w2 >> 4) * 64;
  int tx = threadIdx.x & 63, ty = threadIdx.x >> 6;
  #pragma unroll
  for (int s = 0; s < 64; s += 4)
    t[ty + s][tx] = W[(size_t)(k0 + ty + s) * DM + n0 + tx];
  __syncthreads();
  #pragma unroll
  for (int s = 0; s < 64; s += 4)
    WT[(size_t)(n0 + ty + s) * DM + k0 + tx] = f2bf(t[tx][ty + s]);
}

// ---------------- 256x256 counted-vmcnt MFMA GEMM (K=1024 fixed) — R3/R17 structure ----------------
// PERMANENTLY PARKED (3 strikes): measured-best 133.6-134.2 us (QKV), MfmaUtil ~32.5%,
// 0 bank conflicts. 8-phase (R4/R5 null x2), 128^2 (R11 regress), BK=32 (R18 regress,
// 9.4M conflicts from swizzle mismatch). This exact version measured in the 307.1us run.
template<int QKV>
__global__ __launch_bounds__(512, 2) void gemm256_kernel(
    const u16* __restrict__ A, const u16* __restrict__ BT,
    const float* __restrict__ biasq, const float* __restrict__ biask, const float* __restrict__ biasv,
    u16* __restrict__ oq, u16* __restrict__ ok, u16* __restrict__ ov,
    float* __restrict__ outf,
    float* __restrict__ sumQ, float* __restrict__ sumK, int NBY)
{
  // LDS: A slot0 [0,32K), A slot1 [32K,64K), B slot0 [64K,96K), B slot1 [96K,128K)
  __shared__ __align__(16) u16 smem[65536];
  char* smb = (char*)smem;
  int tid = threadIdx.x;
  int wave = tid >> 6, lane = tid & 63;
  int wm = wave >> 2, wn = wave & 3;          // 2 x 4 wave grid
  int nwg = gridDim.x;
  int q8 = nwg >> 3;
  int id = blockIdx.x;
  int id2 = (id & 7) * q8 + (id >> 3);
  int bx = id2 / NBY, by = id2 % NBY;
  int m0 = bx * 256, n0 = by * 256;
  int srcq = (tid & 7) ^ ((tid >> 3) & 7);
  const u16* aRow = A  + (size_t)(m0 + (tid >> 3)) * 1024 + srcq * 8;
  const u16* bRow = BT + (size_t)(n0 + (tid >> 3)) * 1024 + srcq * 8;

  f32x4 acc[8][4];
  #pragma unroll
  for (int i=0;i<8;i++)
    #pragma unroll
    for (int j=0;j<4;j++) acc[i][j] = (f32x4){0.f,0.f,0.f,0.f};

  int fr = lane & 15, q = lane >> 4;
  int aoff0 = fr*128 + (((q ^ (lane&3)) + 4*((lane>>2)&1)) << 4);
  int aoff1 = fr*128 + (((q ^ (lane&3)) + 4*(1 ^ ((lane>>2)&1))) << 4);

  #define STAGE(s, t) { \
    _Pragma("unroll") \
    for (int i_ = 0; i_ < 4; i_++){ \
      gload16(aRow + (size_t)(t)*64 + (size_t)i_*65536, smb + (s)*32768 + i_*8192 + tid*16); \
      gload16(bRow + (size_t)(t)*64 + (size_t)i_*65536, smb + 65536 + (s)*32768 + i_*8192 + tid*16); \
    } }

  #define COMPUTE(s) { \
    const char* Ab_ = smb + (s)*32768 + wm*16384; \
    const char* Bb_ = smb + 65536 + (s)*32768 + wn*8192; \
    _Pragma("unroll") \
    for (int kk_ = 0; kk_ < 2; kk_++){ \
      int off_ = kk_ ? aoff1 : aoff0; \
      s16x8 af_[8], bf_[4]; \
      _Pragma("unroll") \
      for (int mi_ = 0; mi_ < 8; mi_++) af_[mi_] = *(const s16x8*)(Ab_ + mi_*2048 + off_); \
      _Pragma("unroll") \
      for (int ni_ = 0; ni_ < 4; ni_++) bf_[ni_] = *(const s16x8*)(Bb_ + ni_*2048 + off_); \
      _Pragma("unroll") \
      for (int mi_ = 0; mi_ < 8; mi_++) \
        _Pragma("unroll") \
        for (int ni_ = 0; ni_ < 4; ni_++) \
          acc[mi_][ni_] = mfma16(af_[mi_], bf_[ni_], acc[mi_][ni_]); \
    } }

  STAGE(0, 0)
  STAGE(1, 1)
  for (int t = 0; t < 14; t++){
    asm volatile("s_waitcnt vmcnt(8)" ::: "memory");
    __builtin_amdgcn_s_barrier();
    asm volatile("" ::: "memory");
    COMPUTE(t & 1)
    asm volatile("s_waitcnt lgkmcnt(0)" ::: "memory");
    __builtin_amdgcn_s_barrier();
    asm volatile("" ::: "memory");
    STAGE(t & 1, t + 2)
  }
  asm volatile("s_waitcnt vmcnt(8)" ::: "memory");
  __builtin_amdgcn_s_barrier();
  asm volatile("" ::: "memory");
  COMPUTE(0)
  asm volatile("s_waitcnt vmcnt(0)" ::: "memory");
  __builtin_amdgcn_s_barrier();
  asm volatile("" ::: "memory");
  COMPUTE(1)

  // epilogue
  int colblk = n0 + wn*64;
  int which  = QKV ? (colblk >> 10) : 0;          // 0=q 1=k 2=v
  int cl0    = QKV ? (colblk & 1023) : colblk;
  const float* bias = QKV ? (which==0 ? biasq : (which==1 ? biask : biasv)) : biasq;
  u16* outp = QKV ? (which==0 ? oq : (which==1 ? ok : ov)) : (u16*)0;
  float cs0[4] = {0.f,0.f,0.f,0.f}, cs1[4] = {0.f,0.f,0.f,0.f};
  #pragma unroll
  for (int mi = 0; mi < 8; mi++){
    int row = m0 + wm*128 + mi*16 + (lane>>4)*4;
    #pragma unroll
    for (int ni = 0; ni < 4; ni++){
      int cl = cl0 + ni*16 + fr;
      float bv = bias[cl];
      #pragma unroll
      for (int r = 0; r < 4; r++){
        float val = acc[mi][ni][r] + bv;
        if (QKV){
          if (which < 2) val = sigmoidf_(val);
          outp[(size_t)(row + r) * 1024 + cl] = f2bf(val);
          if (which < 2){ if (mi < 4) cs0[ni] += val; else cs1[ni] += val; }
        } else {
          outf[(size_t)(row + r) * 1024 + cl] = val;
        }
      }
    }
  }
  if (QKV && which < 2){
    float* sums = (which==0) ? sumQ : sumK;
    int bh = (m0 >> 12) * H_ + ((colblk & 1023) >> 6);
    int sc0 = ((m0 & 4095) >> 6) + wm*2;
    #pragma unroll
    for (int h2 = 0; h2 < 2; h2++){
      #pragma unroll
      for (int ni = 0; ni < 4; ni++){
        float s = h2 ? cs1[ni] : cs0[ni];
        s += __shfl_xor(s, 16);
        s += __shfl_xor(s, 32);
        if (lane < 16) sums[((size_t)bh*NSC + sc0 + h2)*64 + ni*16 + fr] = s;
      }
    }
  }
  #undef STAGE
  #undef COMPUTE
}

// ---------------- fused sink_incoming/source_outgoing + mod chunk sums (R16) ----------------
__global__ __launch_bounds__(128) void siso_fused_kernel(
    const u16* __restrict__ q, const u16* __restrict__ k,
    const float* __restrict__ sumQ, const float* __restrict__ sumK,
    float* __restrict__ si, float* __restrict__ so,
    float* __restrict__ sumQsi, float* __restrict__ sumKso)
{
  __shared__ u16 cq[64*64];
  __shared__ u16 ck[64*64];
  __shared__ float siv[64], sov[64];
  int bhc = blockIdx.x; int bh = bhc >> 6, sc = bhc & 63;
  int b = bh >> 4, h = bh & 15;
  int tid = threadIdx.x, w = tid >> 6, lane = tid & 63;
  size_t gbase = ((size_t)(b*L_ + sc*SC))*DM + h*D_;
  size_t lb = (size_t)bh*L_ + sc*SC;
  const u16* src = w ? k : q;
  u16* ldsT = w ? ck : cq;
  float run = prefix_sum64(w ? sumK : sumQ, bh, sc, lane);
  // P0: stage raw tile, swizzled
  {
    int r8 = lane >> 3, c8 = (lane & 7) * 8;
    #pragma unroll
    for (int j = 0; j < 8; j++){
      int l = j*8 + r8;
      uint4 u = *(const uint4*)(src + gbase + (size_t)l*DM + c8);
      const u16* up = (const u16*)&u;
      #pragma unroll
      for (int e = 0; e < 8; e++)
        ldsT[l*64 + ((c8 + e) ^ (l & 31))] = up[e];
    }
  }
  __syncthreads();
  // P1: column cumsum in place (lane = d)
  {
    for (int l = 0; l < SC; l++){
      int sw = lane ^ (l & 31);
      run += bf2f(ldsT[l*64 + sw]);
      ldsT[l*64 + sw] = f2bf(run);
    }
  }
  __syncthreads();
  // P2: row dots
  uint4 rowreg[8];
  {
    int l = lane;
    const u16* row = src + gbase + (size_t)l*DM;
    #pragma unroll
    for (int j=0;j<8;j++) rowreg[j] = ((const uint4*)row)[j];
    const u16* rp = (const u16*)rowreg;
    const u16* other = w ? cq : ck;
    float acc = 0.f;
    #pragma unroll
    for (int d = 0; d < 64; d++){
      int sw = d ^ (l & 31);
      acc += (bf2f(rp[d])+EPSF) * (bf2f(other[l*64+sw])+EPSF);
    }
    float n = (float)(sc*SC + l + 1);
    float vv = n / acc;
    if (w == 0){ si[lb+l] = vv; siv[l] = vv; }
    else       { so[lb+l] = vv; sov[l] = vv; }
  }
  __syncthreads();
  // P2b: raw rows back over dead cumsums
  {
    int l = lane;
    const u16* rp = (const u16*)rowreg;
    #pragma unroll
    for (int d = 0; d < 64; d++)
      ldsT[l*64 + (d ^ (l & 31))] = rp[d];
  }
  __syncthreads();
  // P3: column mod-sums (lane = d)
  {
    const float* sv = w ? sov : siv;
    float s = 0.f;
    for (int l = 0; l < SC; l++){
      int sw = lane ^ (l & 31);
      s += bf2f(ldsT[l*64 + sw]) * sv[l];
    }
    if (w == 0) sumQsi[bhc*64 + lane] = s;
    else        sumKso[bhc*64 + lane] = s;
  }
}

// ---------------- fused conserved_sink/source -> sall, csrc + exp chunk sums (R16) ----------------
__global__ __launch_bounds__(128) void cons_fused_kernel(
    const u16* __restrict__ q, const u16* __restrict__ k,
    const float* __restrict__ si, const float* __restrict__ so,
    const float* __restrict__ sumQsi, const float* __restrict__ sumKso,
    float* __restrict__ csrc, float* __restrict__ sall, float* __restrict__ csSum)
{
  __shared__ u16 cq[64*64];
  __shared__ u16 ck[64*64];
  __shared__ float siv[64], sov[64];
  int bhc = blockIdx.x; int bh = bhc >> 6, sc = bhc & 63;
  int b = bh >> 4, h = bh & 15;
  int tid = threadIdx.x, w = tid >> 6, lane = tid & 63;
  size_t gbase = ((size_t)(b*L_ + sc*SC))*DM + h*D_;
  size_t lb = (size_t)bh*L_ + sc*SC;
  const u16* src = w ? k : q;
  u16* ldsT = w ? ck : cq;
  if (w == 0) siv[lane] = si[lb + lane];
  else        sov[lane] = so[lb + lane];
  float run = prefix_sum64(w ? sumKso : sumQsi, bh, sc, lane);
  // P0: stage raw tile, swizzled
  {
    int r8 = lane >> 3, c8 = (lane & 7) * 8;
    #pragma unroll
    for (int j = 0; j < 8; j++){
      int l = j*8 + r8;
      uint4 u = *(const uint4*)(src + gbase + (size_t)l*DM + c8);
      const u16* up = (const u16*)&u;
      #pragma unroll
      for (int e = 0; e < 8; e++)
        ldsT[l*64 + ((c8 + e) ^ (l & 31))] = up[e];
    }
  }
  __syncthreads();
  // P1: weighted column cumsum in place
  {
    const float* sv = w ? sov : siv;
    for (int l = 0; l < SC; l++){
      int sw = lane ^ (l & 31);
      run += bf2f(ldsT[l*64 + sw]) * sv[l];
      ldsT[l*64 + sw] = f2bf(run);
    }
  }
  __syncthreads();
  // P2: row dots
  {
    int l = lane;
    const u16* row = src + gbase + (size_t)l*DM;
    uint4 rr[8];
    #pragma unroll
    for (int j=0;j<8;j++) rr[j] = ((const uint4*)row)[j];
    const u16* rp = (const u16*)rr;
    const u16* other = w ? cq : ck;
    float acc = 0.f;
    #pragma unroll
    for (int d = 0; d < 64; d++){
      int sw = d ^ (l & 31);
      acc += (bf2f(rp[d])+EPSF) * (bf2f(other[l*64+sw])+EPSF);
    }
    float inv = 1.0f / (float)(sc*SC + l + 1);
    if (w == 0){
      sall[lb+l] = sigmoidf_(acc * inv);
    } else {
      float cs = acc * inv;
      csrc[lb+l] = cs;
      float e = __expf(cs);
      #pragma unroll
      for (int off = 32; off > 0; off >>= 1) e += __shfl_xor(e, off);
      if (lane == 0) csSum[bhc] = e;
    }
  }
}

// ---------------- per-chunk VK sums via MFMA + scomp fused; bf16 chunk output ----------------
__global__ __launch_bounds__(256) void vk_chunk_kernel(
    const u16* __restrict__ k, const u16* __restrict__ v,
    const float* __restrict__ csrc, const float* __restrict__ csSum,
    float* __restrict__ scomp, u16* __restrict__ vkc16){
  __shared__ __align__(16) u16 vt[64*128];   // (v*scomp)^T [m][l] swz
  __shared__ __align__(16) u16 kt[64*128];   // k^T [d][l] swz
  __shared__ float scmpv[128];
  int bhc = blockIdx.x; int bh = bhc >> 5, c = bhc & 31;
  int b = bh >> 4, h = bh & 15;
  int tid = threadIdx.x, wave = tid >> 6, lane = tid & 63;
  size_t gbase = ((size_t)(b * L_ + c * CS)) * DM + h * D_;
  // Phase A: scmp for scan-chunks sc = 2c + {0,1}
  if (wave < 2){
    int sc = c*2 + wave;
    float v2 = (lane < sc) ? csSum[bh*NSC + lane] : 0.f;
    #pragma unroll
    for (int o = 32; o > 0; o >>= 1) v2 += __shfl_xor(v2, o);
    float off = v2;
    size_t idx = (size_t)bh * L_ + sc * SC + lane;
    float cs = __expf(csrc[idx]);
    float run = cs;
    #pragma unroll
    for (int o = 1; o < 64; o <<= 1){
      float t = __shfl_up(run, o);
      if (lane >= o) run += t;
    }
    float sm = cs / (off + run) * (float)(sc*SC + lane + 1);
    scomp[idx] = sm;
    scmpv[wave*64 + lane] = sm;
  }
  __syncthreads();
  // Phase B: stage transposed tiles (v scaled by scmp from LDS)
  {
    int r = tid >> 1;            // source row l = 0..127
    int cc = (tid & 1) * 32;     // d-half
    float vscale = scmpv[r];
    #pragma unroll
    for (int j = 0; j < 4; j++){
      uint4 ku = *(const uint4*)(k + gbase + (size_t)r * DM + cc + j*8);
      uint4 vu = *(const uint4*)(v + gbase + (size_t)r * DM + cc + j*8);
      const u16* kp = (const u16*)&ku; const u16* vp = (const u16*)&vu;
      #pragma unroll
      for (int e = 0; e < 8; e++){
        int m = cc + j*8 + e;
        int idx = m*128 + ((((r >> 3) ^ (m & 7)) << 3) | (r & 7));
        vt[idx] = f2bf(bf2f(vp[e]) * vscale);
        kt[idx] = kp[e];
      }
    }
  }
  __syncthreads();
  int fr = lane & 15, q = lane >> 4;
  int mt = wave;                 // m-tile (16 rows) per wave
  f32x4 acc[4];
  #pragma unroll
  for (int i = 0; i < 4; i++) acc[i] = (f32x4){0.f,0.f,0.f,0.f};
  #pragma unroll
  for (int ks = 0; ks < 4; ks++){
    int lc = ks*4 + q;           // logical 16B l-chunk
    int off = ((lc ^ (fr & 7)) << 3);
    s16x8 av = *(const s16x8*)&vt[(mt*16 + fr)*128 + off];
    #pragma unroll
    for (int nt = 0; nt < 4; nt++){
      s16x8 bk = *(const s16x8*)&kt[(nt*16 + fr)*128 + off];
      acc[nt] = mfma16(av, bk, acc[nt]);
    }
  }
  u16* outp = vkc16 + (size_t)bhc * (D_*D_);
  #pragma unroll
  for (int nt = 0; nt < 4; nt++)
    #pragma unroll
    for (int r = 0; r < 4; r++)
      outp[(mt*16 + q*4 + r)*64 + nt*16 + fr] = f2bf(acc[nt][r]);
}

// ---------------- exclusive scan of VK over chunks: bf16 in -> bf16 prefix out ----------------
__global__ __launch_bounds__(256) void vk_scan_kernel(const u16* __restrict__ vkc16, u16* __restrict__ vkb){
  int idx = blockIdx.x * 256 + threadIdx.x;   // over BH*4096
  int bh = idx >> 12;
  int e  = idx & 4095;
  size_t base = ((size_t)bh * NC) * 4096 + e;
  float run = 0.f;
  for (int g = 0; g < NC; g += 16){
    u16 tv[16];
    #pragma unroll
    for (int j = 0; j < 16; j++) tv[j] = vkc16[base + (size_t)(g + j) * 4096];
    #pragma unroll
    for (int j = 0; j < 16; j++){
      vkb[base + (size_t)(g + j) * 4096] = f2bf(run);
      run += bf2f(tv[j]);
    }
  }
}

// ---------------- causal attention per (bh, chunk) — R17 (overlapped, measured good) ----------------
__global__ __launch_bounds__(256) void attn_kernel(
    const u16* __restrict__ q, const u16* __restrict__ k, const u16* __restrict__ v,
    const float* __restrict__ si, const float* __restrict__ scomp, const float* __restrict__ salloc,
    const u16* __restrict__ vkb, u16* __restrict__ attnout)
{
  __shared__ __align__(16) u16 qs[128*64];    // qmod rows [l][d] swz; reused as ss0
  __shared__ __align__(16) u16 ks2[128*64];   // k rows    [j][d] swz
  __shared__ __align__(16) u16 vts[64*128];   // (v*scomp)^T [m][j] swz
  __shared__ __align__(16) u16 vks[64*64];    // VKprev [m][d] swz
  __shared__ __align__(16) u16 ss[128*64];    // S strip for jt2=1 (ss1)
  int bhc = blockIdx.x; int bh = bhc >> 5, c = bhc & 31;
  int b = bh >> 4, h = bh & 15;
  int tid = threadIdx.x, wave = tid >> 6, lane = tid & 63;
  size_t gbase = ((size_t)(b * L_ + c * CS)) * DM + h * D_;
  size_t sbase = (size_t)bh * L_ + c * CS;
  {
    int r = tid >> 1;
    int cc = (tid & 1) * 32;
    int l = c * CS + r;
    float qscale = si[sbase + r] / (float)(l + 1);
    float vscale = scomp[sbase + r];
    #pragma unroll
    for (int j = 0; j < 4; j++){
      int d0 = cc + j*8;
      uint4 qu = *(const uint4*)(q + gbase + (size_t)r * DM + d0);
      uint4 kuv = *(const uint4*)(k + gbase + (size_t)r * DM + d0);
      uint4 vu = *(const uint4*)(v + gbase + (size_t)r * DM + d0);
      const u16* qp = (const u16*)&qu; const u16* vp = (const u16*)&vu;
      u16 tmp[8];
      #pragma unroll
      for (int e = 0; e < 8; e++) tmp[e] = f2bf(bf2f(qp[e]) * qscale);
      int csw = ((d0 >> 3) ^ (r & 7)) << 3;           // swizzled d-chunk
      *(uint4*)&qs[r*64 + csw]  = *(uint4*)tmp;
      *(uint4*)&ks2[r*64 + csw] = kuv;
      #pragma unroll
      for (int e = 0; e < 8; e++){
        int m = d0 + e;
        int jsw = (((r >> 3) ^ (m & 7)) << 3) | (r & 7);  // swizzled j position
        vts[m*128 + jsw] = f2bf(bf2f(vp[e]) * vscale);
      }
    }
    const u16* vkp = vkb + (size_t)bhc * (D_*D_) + tid * 16;
    int m = tid >> 2, dq = (tid & 3) * 2;               // two d-chunks per thread
    int o0 = ((dq     ^ (m & 7)) << 3);
    int o1 = (((dq+1) ^ (m & 7)) << 3);
    *(uint4*)&vks[m*64 + o0] = *(const uint4*)(vkp);
    *(uint4*)&vks[m*64 + o1] = *(const uint4*)(vkp + 8);
  }
  __syncthreads();                 // B0: staging visible
  int t0 = wave, t1 = 7 - wave;    // balanced l-tile pair per wave
  int fr = lane & 15, qh = lane >> 4;
  int f7 = fr & 7;
  f32x4 acc[2][4];
  #pragma unroll
  for (int i=0;i<2;i++)
    #pragma unroll
    for (int j=0;j<4;j++) acc[i][j] = (f32x4){0.f,0.f,0.f,0.f};
  s16x8 aq[2][2];
  #pragma unroll
  for (int ti = 0; ti < 2; ti++){
    int t = ti ? t1 : t0;
    #pragma unroll
    for (int kk = 0; kk < 2; kk++){
      int oc = (((kk*4 + qh) ^ f7) << 3);
      aq[ti][kk] = *(const s16x8*)&qs[(t*16 + fr)*64 + oc];
    }
  }
  __syncthreads();                 // B-A: all aq loads done; qs region now dead
  // inter-chunk MFMA + QK half0 (S -> qs region)
  #pragma unroll
  for (int mt = 0; mt < 4; mt++){
    #pragma unroll
    for (int kk = 0; kk < 2; kk++){
      int oc = (((kk*4 + qh) ^ f7) << 3);
      s16x8 bv = *(const s16x8*)&vks[(mt*16 + fr)*64 + oc];
      acc[0][mt] = mfma16(aq[0][kk], bv, acc[0][mt]);
      acc[1][mt] = mfma16(aq[1][kk], bv, acc[1][mt]);
    }
  }
  #define QK_HALF(jt2, dst) \
    _Pragma("unroll") \
    for (int ti = 0; ti < 2; ti++){ \
      int t = ti ? t1 : t0; \
      _Pragma("unroll") \
      for (int u = 0; u < 4; u++){ \
        int jj = (jt2)*4 + u; \
        f32x4 sacc = (f32x4){0.f,0.f,0.f,0.f}; \
        if (jj <= t){ \
          _Pragma("unroll") \
          for (int kk = 0; kk < 2; kk++){ \
            int oc = (((kk*4 + qh) ^ f7) << 3); \
            s16x8 bkf = *(const s16x8*)&ks2[(jj*16 + fr)*64 + oc]; \
            sacc = mfma16(aq[ti][kk], bkf, sacc); \
          } \
        } \
        int lrow = t*16 + qh*4; \
        int jcol = jj*16 + fr; \
        int cst = u*2 + (fr >> 3); \
        _Pragma("unroll") \
        for (int r = 0; r < 4; r++){ \
          float sv = (jcol <= lrow + r) ? sacc[r] : 0.f; \
          int row = lrow + r; \
          dst[row*64 + (((cst ^ (row & 7)) << 3) | f7)] = f2bf(sv); \
        } \
      } \
    }
  #define PV_HALF(jt2, srcb) \
    _Pragma("unroll") \
    for (int ti = 0; ti < 2; ti++){ \
      int t = ti ? t1 : t0; \
      _Pragma("unroll") \
      for (int ks = 0; ks < 2; ks++){ \
        if ((jt2)*64 + ks*32 <= t*16 + 15){ \
          int ocs = (((ks*4 + qh) ^ f7) << 3); \
          s16x8 as = *(const s16x8*)&srcb[(t*16 + fr)*64 + ocs]; \
          _Pragma("unroll") \
          for (int mt = 0; mt < 4; mt++){ \
            int lc = (jt2)*8 + ks*4 + qh; \
            int ocv = ((lc ^ f7) << 3); \
            s16x8 bvv = *(const s16x8*)&vts[(mt*16 + fr)*128 + ocv]; \
            acc[ti][mt] = mfma16(as, bvv, acc[ti][mt]); \
          } \
        } \
      } \
    }
  QK_HALF(0, qs)
  __syncthreads();                 // B-B: ss0 (qs region) complete
  QK_HALF(1, ss)                   // overlaps PV0 below (disjoint buffers)
  PV_HALF(0, qs)
  __syncthreads();                 // B-C: ss1 complete, PV0 done
  PV_HALF(1, ss)
  #undef QK_HALF
  #undef PV_HALF
  // epilogue: * sink_allocation, write bf16 [B,L,DM]
  #pragma unroll
  for (int ti = 0; ti < 2; ti++){
    int t = ti ? t1 : t0;
    int lrow = t*16 + qh*4;
    #pragma unroll
    for (int r = 0; r < 4; r++){
      float sa = salloc[sbase + lrow + r];
      size_t orow = ((size_t)(b * L_ + c * CS + lrow + r)) * DM + h * D_;
      #pragma unroll
      for (int mt = 0; mt < 4; mt++){
        attnout[orow + mt*16 + fr] = f2bf(acc[ti][mt][r] * sa);
      }
    }
  }
}

extern "C" void kernel_launch(void* const* d_in, const int* in_sizes, int n_in,
                              void* d_out, int out_size, void* d_ws, size_t ws_size,
                              hipStream_t stream){
  (void)in_sizes; (void)n_in; (void)out_size; (void)ws_size;
  const float* x  = (const float*)d_in[0];
  const float* Wq = (const float*)d_in[1];
  const float* bq = (const float*)d_in[2];
  const float* Wk = (const float*)d_in[3];
  const float* bk = (const float*)d_in[4];
  const float* Wv = (const float*)d_in[5];
  const float* bv = (const float*)d_in[6];
  const float* Wo = (const float*)d_in[7];
  const float* bo = (const float*)d_in[8];

  char* p = (char*)d_ws;
  auto carve = [&](size_t bytes) -> void* {
    void* r = (void*)p; p += (bytes + 255) & ~(size_t)255; return r;
  };
  u16* xb    = (u16*)carve((size_t)N_*DM*2);
  u16* wqkvT = (u16*)carve((size_t)3*DM*DM*2);
  u16* woT   = (u16*)carve((size_t)DM*DM*2);
  u16* qb  = (u16*)carve((size_t)N_*DM*2);
  u16* kb  = (u16*)carve((size_t)N_*DM*2);
  u16* vb  = (u16*)carve((size_t)N_*DM*2);
  u16* ao  = (u16*)carve((size_t)N_*DM*2);
  float* si   = (float*)carve((size_t)BH*L_*4);
  float* so   = (float*)carve((size_t)BH*L_*4);
  float* csrc = (float*)carve((size_t)BH*L_*4);
  float* sall = (float*)carve((size_t)BH*L_*4);
  float* scmp = (float*)carve((size_t)BH*L_*4);
  float* sumQ   = (float*)carve((size_t)BH*NSC*D_*4);
  float* sumK   = (float*)carve((size_t)BH*NSC*D_*4);
  float* sumQsi = (float*)carve((size_t)BH*NSC*D_*4);
  float* sumKso = (float*)carve((size_t)BH*NSC*D_*4);
  float* csSum  = (float*)carve((size_t)BH*NSC*4);
  u16*   vkc16  = (u16*)carve((size_t)BH*NC*(size_t)(D_*D_)*2);
  u16*   vkb    = (u16*)carve((size_t)BH*NC*(size_t)(D_*D_)*2);

  // 1. prep: cvt + 4 weight transposes (one launch)
  prep_kernel<<<16384 + 4*256, 256, 0, stream>>>(x, Wq, Wk, Wv, Wo, xb, wqkvT, woT);
  // 2. fused q,k,v projection (one 16384x3072x1024 GEMM) + per-scan-chunk sums
  gemm256_kernel<1><<<dim3((N_/256)*(3*DM/256)), 512, 0, stream>>>(
      xb, wqkvT, bq, bk, bv, qb, kb, vb, nullptr, sumQ, sumK, 3*DM/256);
  // 3. normalizer pipeline (chunk prefixes inlined)
  siso_fused_kernel<<<BH*NSC, 128, 0, stream>>>(qb, kb, sumQ, sumK, si, so, sumQsi, sumKso);
  cons_fused_kernel<<<BH*NSC, 128, 0, stream>>>(qb, kb, si, so, sumQsi, sumKso, csrc, sall, csSum);
  // 4. causal linear attention (scomp fused into vk_chunk; bf16 VK chain)
  vk_chunk_kernel<<<BH*NC, 256, 0, stream>>>(kb, vb, csrc, csSum, scmp, vkc16);
  vk_scan_kernel<<<(BH*D_*D_)/256, 256, 0, stream>>>(vkc16, vkb);
  attn_kernel<<<BH*NC, 256, 0, stream>>>(qb, kb, vb, si, scmp, sall, vkb, ao);
  // 5. output projection
  gemm256_kernel<0><<<dim3((N_/256)*(DM/256)), 512, 0, stream>>>(
      ao, woT, bo, bo, bo, nullptr, nullptr, nullptr, (float*)d_out, nullptr, nullptr, DM/256);
}